// Round 1
// baseline (1267.563 us; speedup 1.0000x reference)
//
#include <hip/hip_runtime.h>
#include <hip/hip_bf16.h>
#include <math.h>

#define S_LEN 2048
#define E_DIM 1024
#define NH 8
#define DH 128
#define E3 3072

__device__ __forceinline__ float logsigf(float x){
  // log(sigmoid(x)) = min(x,0) - log1p(exp(-|x|))
  return fminf(x, 0.f) - log1pf(expf(-fabsf(x)));
}

// ---------------- Kernel A: gate pre-activations -------------------
// ig[h][t] = dot(gate_in[t], igate_w[h]) + igate_b[h]
// lsf[h][t] = log_sigmoid(dot(gate_in[t], fgate_w[h]) + fgate_b[h])
__global__ __launch_bounds__(256) void gates_kernel(
    const float* __restrict__ q, const float* __restrict__ k, const float* __restrict__ v,
    const float* __restrict__ igw, const float* __restrict__ igb,
    const float* __restrict__ fgw, const float* __restrict__ fgb,
    float* __restrict__ ig_out, float* __restrict__ lsf_out){
  const int t = blockIdx.x;
  const int tid = threadIdx.x;
  const float* qr = q + (size_t)t*E_DIM;
  const float* kr = k + (size_t)t*E_DIM;
  const float* vr = v + (size_t)t*E_DIM;
  float accI[NH], accF[NH];
  #pragma unroll
  for (int o=0;o<NH;++o){ accI[o]=0.f; accF[o]=0.f; }
  for (int j=tid; j<E3; j+=256){
    float e = (j < E_DIM) ? qr[j] : (j < 2*E_DIM ? kr[j-E_DIM] : vr[j-2*E_DIM]);
    #pragma unroll
    for (int o=0;o<NH;++o){
      accI[o] = fmaf(e, igw[o*E3+j], accI[o]);
      accF[o] = fmaf(e, fgw[o*E3+j], accF[o]);
    }
  }
  #pragma unroll
  for (int o=0;o<NH;++o){
    #pragma unroll
    for (int off=32; off>0; off>>=1){
      accI[o] += __shfl_down(accI[o], off, 64);
      accF[o] += __shfl_down(accF[o], off, 64);
    }
  }
  __shared__ float red[4][16];
  const int wave = tid>>6, lane = tid&63;
  if (lane==0){
    #pragma unroll
    for (int o=0;o<NH;++o){ red[wave][o]=accI[o]; red[wave][NH+o]=accF[o]; }
  }
  __syncthreads();
  if (tid < 16){
    float s = red[0][tid]+red[1][tid]+red[2][tid]+red[3][tid];
    if (tid < NH){
      ig_out[tid*S_LEN + t] = s + igb[tid];
    } else {
      int h = tid - NH;
      lsf_out[h*S_LEN + t] = logsigf(s + fgb[h]);
    }
  }
}

// ---------------- Kernel B: per-head scans -------------------------
// cs[t] = inclusive cumsum of lsf ; m[t] = ig[t]-cs[t] ; M[t] = inclusive prefix-max of m
__global__ __launch_bounds__(256) void scan_kernel(
    const float* __restrict__ ig, const float* __restrict__ lsf,
    float* __restrict__ cs_out, float* __restrict__ M_out, float* __restrict__ m_out){
  const int h = blockIdx.x;
  const int tid = threadIdx.x;
  __shared__ float tt[256];
  const int base = tid*8;
  const float* src = lsf + h*S_LEN;
  float loc[8]; float tot = 0.f;
  #pragma unroll
  for (int i=0;i<8;++i){ tot += src[base+i]; loc[i]=tot; }
  tt[tid]=tot; __syncthreads();
  for (int off=1; off<256; off<<=1){
    float add = (tid>=off)? tt[tid-off] : 0.f;
    __syncthreads();
    tt[tid] += add;
    __syncthreads();
  }
  const float excl = tt[tid] - tot;
  float csv[8];
  #pragma unroll
  for (int i=0;i<8;++i){ csv[i] = excl + loc[i]; cs_out[h*S_LEN+base+i]=csv[i]; }
  const float* igp = ig + h*S_LEN;
  float mloc[8], mval[8]; float mtot = -INFINITY;
  #pragma unroll
  for (int i=0;i<8;++i){
    float m = igp[base+i] - csv[i];
    mval[i] = m;
    mtot = fmaxf(mtot, m);
    mloc[i] = mtot;
  }
  __syncthreads();
  tt[tid]=mtot; __syncthreads();
  for (int off=1; off<256; off<<=1){
    float add = (tid>=off)? tt[tid-off] : -INFINITY;
    __syncthreads();
    tt[tid] = fmaxf(tt[tid], add);
    __syncthreads();
  }
  const float exclm = (tid>0)? tt[tid-1] : -INFINITY;
  #pragma unroll
  for (int i=0;i<8;++i){
    M_out[h*S_LEN+base+i] = fmaxf(exclm, mloc[i]);
    m_out[h*S_LEN+base+i] = mval[i];
  }
}

// ---------------- Kernel C: main causal tile loop ------------------
#define TQ 32
#define TK 32
#define LPAD 132   // 128 + 4: float4-aligned rows, bank offset 4 per row

__global__ __launch_bounds__(256) void mlstm_main(
    const float* __restrict__ q, const float* __restrict__ k, const float* __restrict__ v,
    const float* __restrict__ cs, const float* __restrict__ Mx, const float* __restrict__ mb,
    const float* __restrict__ nw, float* __restrict__ out){
  const int h = blockIdx.y;
  const int qt = blockIdx.x;
  const int tq0 = qt*TQ;
  const int tid = threadIdx.x;
  const int tl = tid >> 3;   // local query row 0..31
  const int g  = tid & 7;    // column group 0..7

  __shared__ float Qs[TQ][LPAD];
  __shared__ float Ks[TK][LPAD];
  __shared__ float Vs[TK][LPAD];
  __shared__ float Csh[TQ][33];
  __shared__ float msh[TK];
  __shared__ float redA[TQ][8];
  __shared__ float redB[TQ][8];
  __shared__ float invn[TQ];
  __shared__ float eneg[TQ];
  __shared__ float Mtt[TQ];
  __shared__ float meansh[TQ];
  __shared__ float rstdsh[TQ];

  const float scale = 0.08838834764831845f; // 1/sqrt(128)
  for (int idx = tid; idx < TQ*32; idx += 256){
    int r = idx >> 5, c4 = (idx & 31) * 4;
    const float4 val = *(const float4*)(q + (size_t)(tq0+r)*E_DIM + h*DH + c4);
    Qs[r][c4+0]=val.x*scale; Qs[r][c4+1]=val.y*scale;
    Qs[r][c4+2]=val.z*scale; Qs[r][c4+3]=val.w*scale;
  }
  if (tid < TQ){
    float c = cs[h*S_LEN + tq0 + tid];
    float m = Mx[h*S_LEN + tq0 + tid];
    Mtt[tid] = m;
    eneg[tid] = expf(-(c+m));   // bounded by exp(-ig[t]), no overflow
  }
  float acc[16];
  #pragma unroll
  for (int i=0;i<16;++i) acc[i]=0.f;
  float rs_part = 0.f;

  for (int kt=0; kt<=qt; ++kt){
    const int sk0 = kt*TK;
    __syncthreads();
    for (int idx = tid; idx < TK*32; idx += 256){
      int r = idx >> 5, c4 = (idx & 31)*4;
      const float4 kv = *(const float4*)(k + (size_t)(sk0+r)*E_DIM + h*DH + c4);
      const float4 vv = *(const float4*)(v + (size_t)(sk0+r)*E_DIM + h*DH + c4);
      Ks[r][c4+0]=kv.x; Ks[r][c4+1]=kv.y; Ks[r][c4+2]=kv.z; Ks[r][c4+3]=kv.w;
      Vs[r][c4+0]=vv.x; Vs[r][c4+1]=vv.y; Vs[r][c4+2]=vv.z; Vs[r][c4+3]=vv.w;
    }
    if (tid < TK) msh[tid] = mb[h*S_LEN + sk0 + tid];
    __syncthreads();

    // QK^T: thread computes C[tl][g*4 .. g*4+3]
    float dots[4]={0.f,0.f,0.f,0.f};
    for (int j=0;j<DH;j+=4){
      const float4 qv = *(const float4*)&Qs[tl][j];
      #pragma unroll
      for (int i=0;i<4;++i){
        const float4 kv = *(const float4*)&Ks[g*4+i][j];
        dots[i] += qv.x*kv.x + qv.y*kv.y + qv.z*kv.z + qv.w*kv.w;
      }
    }
    const float Mv = Mtt[tl];
    const int tg = tq0 + tl;
    #pragma unroll
    for (int i=0;i<4;++i){
      const int sl = g*4+i;
      const int sg = sk0 + sl;
      float cv = 0.f;
      if (sg <= tg) cv = dots[i]*expf(msh[sl]-Mv);  // m[s]-M[t] <= 0 for s<=t
      Csh[tl][sl] = cv;
      rs_part += cv;
    }
    __syncthreads();

    // C @ V: thread owns (tl, d = g*16 .. g*16+15)
    const int d0 = g*16;
    for (int s2=0;s2<TK;++s2){
      const float cv = Csh[tl][s2];
      #pragma unroll
      for (int qq=0;qq<4;++qq){
        const float4 vv = *(const float4*)&Vs[s2][d0+qq*4];
        acc[qq*4+0] = fmaf(cv, vv.x, acc[qq*4+0]);
        acc[qq*4+1] = fmaf(cv, vv.y, acc[qq*4+1]);
        acc[qq*4+2] = fmaf(cv, vv.z, acc[qq*4+2]);
        acc[qq*4+3] = fmaf(cv, vv.w, acc[qq*4+3]);
      }
    }
  }

  __syncthreads();
  redA[tl][g] = rs_part;
  __syncthreads();
  if (g==0){
    float rsum = 0.f;
    #pragma unroll
    for (int i=0;i<8;++i) rsum += redA[tl][i];
    invn[tl] = 1.f/(fmaxf(fabsf(rsum), eneg[tl]) + 1e-6f);
  }
  __syncthreads();
  const float inv = invn[tl];
  float hv[16];
  float ps=0.f, ps2=0.f;
  #pragma unroll
  for (int i=0;i<16;++i){ hv[i]=acc[i]*inv; ps+=hv[i]; ps2+=hv[i]*hv[i]; }
  redA[tl][g]=ps; redB[tl][g]=ps2;
  __syncthreads();
  if (g==0){
    float s1=0.f, s2v=0.f;
    #pragma unroll
    for (int i=0;i<8;++i){ s1+=redA[tl][i]; s2v+=redB[tl][i]; }
    float mean = s1 * (1.f/128.f);
    float var  = s2v * (1.f/128.f) - mean*mean;
    meansh[tl]=mean; rstdsh[tl]=rsqrtf(var + 1e-5f);
  }
  __syncthreads();
  const float mean=meansh[tl], rstd=rstdsh[tl];
  const int d0 = g*16;
  float* orow = out + (size_t)(tq0+tl)*E_DIM + h*DH + d0;
  #pragma unroll
  for (int qq=0;qq<4;++qq){
    float4 o4;
    o4.x = (hv[qq*4+0]-mean)*rstd*nw[h*DH+d0+qq*4+0];
    o4.y = (hv[qq*4+1]-mean)*rstd*nw[h*DH+d0+qq*4+1];
    o4.z = (hv[qq*4+2]-mean)*rstd*nw[h*DH+d0+qq*4+2];
    o4.w = (hv[qq*4+3]-mean)*rstd*nw[h*DH+d0+qq*4+3];
    *(float4*)(orow + qq*4) = o4;
  }
}

extern "C" void kernel_launch(void* const* d_in, const int* in_sizes, int n_in,
                              void* d_out, int out_size, void* d_ws, size_t ws_size,
                              hipStream_t stream) {
  const float* q   = (const float*)d_in[0];
  const float* k   = (const float*)d_in[1];
  const float* v   = (const float*)d_in[2];
  const float* igw = (const float*)d_in[3];
  const float* igb = (const float*)d_in[4];
  const float* fgw = (const float*)d_in[5];
  const float* fgb = (const float*)d_in[6];
  const float* nw  = (const float*)d_in[7];
  float* outp = (float*)d_out;

  float* ws  = (float*)d_ws;
  float* ig  = ws;                 // NH*S
  float* lsf = ws + 1*NH*S_LEN;    // NH*S
  float* csb = ws + 2*NH*S_LEN;    // NH*S
  float* Mb  = ws + 3*NH*S_LEN;    // NH*S
  float* mbf = ws + 4*NH*S_LEN;    // NH*S

  gates_kernel<<<S_LEN, 256, 0, stream>>>(q, k, v, igw, igb, fgw, fgb, ig, lsf);
  scan_kernel<<<NH, 256, 0, stream>>>(ig, lsf, csb, Mb, mbf);
  dim3 grid(S_LEN/TQ, NH);
  mlstm_main<<<grid, 256, 0, stream>>>(q, k, v, csb, Mb, mbf, nw, outp);
}

// Round 2
// 98.190 us; speedup vs baseline: 12.9092x; 12.9092x over previous
//
#include <hip/hip_runtime.h>
#include <hip/hip_bf16.h>
#include <math.h>

#define S_LEN 2048
#define E_DIM 1024
#define NHEAD 8
#define DH 128
#define E3 3072

typedef short bf16x8 __attribute__((ext_vector_type(8)));
typedef float f32x4 __attribute__((ext_vector_type(4)));

__device__ __forceinline__ unsigned short f2bf(float f){
  union{float f; unsigned u;} x; x.f = f;
  unsigned r = x.u + 0x7FFF + ((x.u>>16)&1);
  return (unsigned short)(r>>16);
}

__device__ __forceinline__ float logsigf(float x){
  return fminf(x, 0.f) - log1pf(expf(-fabsf(x)));
}

// ---------------- Kernel A: gate pre-activations (f32, unchanged) ----------
__global__ __launch_bounds__(256) void gates_kernel(
    const float* __restrict__ q, const float* __restrict__ k, const float* __restrict__ v,
    const float* __restrict__ igw, const float* __restrict__ igb,
    const float* __restrict__ fgw, const float* __restrict__ fgb,
    float* __restrict__ ig_out, float* __restrict__ lsf_out){
  const int t = blockIdx.x;
  const int tid = threadIdx.x;
  const float* qr = q + (size_t)t*E_DIM;
  const float* kr = k + (size_t)t*E_DIM;
  const float* vr = v + (size_t)t*E_DIM;
  float accI[NHEAD], accF[NHEAD];
  #pragma unroll
  for (int o=0;o<NHEAD;++o){ accI[o]=0.f; accF[o]=0.f; }
  for (int j=tid; j<E3; j+=256){
    float e = (j < E_DIM) ? qr[j] : (j < 2*E_DIM ? kr[j-E_DIM] : vr[j-2*E_DIM]);
    #pragma unroll
    for (int o=0;o<NHEAD;++o){
      accI[o] = fmaf(e, igw[o*E3+j], accI[o]);
      accF[o] = fmaf(e, fgw[o*E3+j], accF[o]);
    }
  }
  #pragma unroll
  for (int o=0;o<NHEAD;++o){
    #pragma unroll
    for (int off=32; off>0; off>>=1){
      accI[o] += __shfl_down(accI[o], off, 64);
      accF[o] += __shfl_down(accF[o], off, 64);
    }
  }
  __shared__ float red[4][16];
  const int wave = tid>>6, lane = tid&63;
  if (lane==0){
    #pragma unroll
    for (int o=0;o<NHEAD;++o){ red[wave][o]=accI[o]; red[wave][NHEAD+o]=accF[o]; }
  }
  __syncthreads();
  if (tid < 16){
    float s = red[0][tid]+red[1][tid]+red[2][tid]+red[3][tid];
    if (tid < NHEAD){
      ig_out[tid*S_LEN + t] = s + igb[tid];
    } else {
      int hh = tid - NHEAD;
      lsf_out[hh*S_LEN + t] = logsigf(s + fgb[hh]);
    }
  }
}

// ---------------- Kernel B: per-head scans (unchanged) ---------------------
__global__ __launch_bounds__(256) void scan_kernel(
    const float* __restrict__ ig, const float* __restrict__ lsf,
    float* __restrict__ cs_out, float* __restrict__ M_out, float* __restrict__ m_out){
  const int h = blockIdx.x;
  const int tid = threadIdx.x;
  __shared__ float tt[256];
  const int base = tid*8;
  const float* src = lsf + h*S_LEN;
  float loc[8]; float tot = 0.f;
  #pragma unroll
  for (int i=0;i<8;++i){ tot += src[base+i]; loc[i]=tot; }
  tt[tid]=tot; __syncthreads();
  for (int off=1; off<256; off<<=1){
    float add = (tid>=off)? tt[tid-off] : 0.f;
    __syncthreads();
    tt[tid] += add;
    __syncthreads();
  }
  const float excl = tt[tid] - tot;
  float csv[8];
  #pragma unroll
  for (int i=0;i<8;++i){ csv[i] = excl + loc[i]; cs_out[h*S_LEN+base+i]=csv[i]; }
  const float* igp = ig + h*S_LEN;
  float mloc[8], mval[8]; float mtot = -INFINITY;
  #pragma unroll
  for (int i=0;i<8;++i){
    float m = igp[base+i] - csv[i];
    mval[i] = m;
    mtot = fmaxf(mtot, m);
    mloc[i] = mtot;
  }
  __syncthreads();
  tt[tid]=mtot; __syncthreads();
  for (int off=1; off<256; off<<=1){
    float add = (tid>=off)? tt[tid-off] : -INFINITY;
    __syncthreads();
    tt[tid] = fmaxf(tt[tid], add);
    __syncthreads();
  }
  const float exclm = (tid>0)? tt[tid-1] : -INFINITY;
  #pragma unroll
  for (int i=0;i<8;++i){
    M_out[h*S_LEN+base+i] = fmaxf(exclm, mloc[i]);
    m_out[h*S_LEN+base+i] = mval[i];
  }
}

// ---------------- Kernel P1: q/k -> bf16 (q pre-scaled by 1/sqrt(dh)) ------
__global__ __launch_bounds__(256) void qkconv(
    const float* __restrict__ q, const float* __restrict__ k,
    ushort* __restrict__ qb, ushort* __restrict__ kb){
  const int i = blockIdx.x*256 + threadIdx.x;   // float4 group
  const float sc = 0.08838834764831845f;
  float4 qv = ((const float4*)q)[i];
  float4 kv = ((const float4*)k)[i];
  ushort4 qo, ko;
  qo.x = f2bf(qv.x*sc); qo.y = f2bf(qv.y*sc); qo.z = f2bf(qv.z*sc); qo.w = f2bf(qv.w*sc);
  ko.x = f2bf(kv.x);    ko.y = f2bf(kv.y);    ko.z = f2bf(kv.z);    ko.w = f2bf(kv.w);
  ((ushort4*)qb)[i] = qo;
  ((ushort4*)kb)[i] = ko;
}

// ---------------- Kernel P2: V transpose -> vt[h][d][s] bf16 ---------------
__global__ __launch_bounds__(256) void vtrans(
    const float* __restrict__ v, ushort* __restrict__ vt){
  const int s0 = blockIdx.x*64, d0 = blockIdx.y*64, h = blockIdx.z;
  __shared__ float T[64][65];
  const int r = threadIdx.x>>2, cq = threadIdx.x&3;
  #pragma unroll
  for (int i=0;i<4;++i){
    int col = cq*16 + i*4;
    float4 val = *(const float4*)(v + (size_t)(s0+r)*E_DIM + h*DH + d0 + col);
    T[r][col]=val.x; T[r][col+1]=val.y; T[r][col+2]=val.z; T[r][col+3]=val.w;
  }
  __syncthreads();
  // thread writes vt row d0+r, s chunk cq*16..+15
  ushort tmp[16];
  #pragma unroll
  for (int i=0;i<16;++i) tmp[i] = f2bf(T[cq*16+i][r]);
  ushort* dst = vt + ((size_t)(h*DH + d0 + r))*S_LEN + s0 + cq*16;
  uint4 o0, o1;
  ushort* p0 = (ushort*)&o0; ushort* p1 = (ushort*)&o1;
  #pragma unroll
  for (int i=0;i<8;++i){ p0[i]=tmp[i]; p1[i]=tmp[8+i]; }
  *(uint4*)dst = o0;
  *(uint4*)(dst+8) = o1;
}

// ---------------- Kernel C: MFMA flash-style main --------------------------
// Block: (h, p). Handles q-tiles qtA=p and qtB=63-p (32 rows each).
// 8 waves: w = {qsel(1) stripe(1) nb(1)}: qsel picks tile, stripe picks 16 rows,
// nb picks the 16-column s-half (QK) / 64-wide dh-half (PV).
__global__ __launch_bounds__(512) void mlstm_mfma(
    const ushort* __restrict__ qb, const ushort* __restrict__ kb,
    const ushort* __restrict__ vt,
    const float* __restrict__ csb, const float* __restrict__ Mxb,
    const float* __restrict__ mbb,
    const float* __restrict__ nw, float* __restrict__ out){
  const int h = blockIdx.x;       // 0..7  (head-per-XCD locality)
  const int p = blockIdx.y;       // 0..31
  const int tid = threadIdx.x;
  const int l = tid & 63, w = tid >> 6;
  const int qsel = w >> 2, stripe = (w>>1)&1, nb = w&1;
  const int qt = qsel ? (63 - p) : p;
  const int t0 = qt*32 + stripe*16;
  const int st = w >> 1;                 // stripe slot 0..3
  const int kt_hi = (t0 + 15) >> 5;
  const int NT = 64 - p;

  __shared__ ushort Kb[2][4096];   // 512 chunks x 16B per buffer
  __shared__ ushort Vb[2][4096];
  __shared__ ushort Pl[4][16][40];
  __shared__ float rsC[4][2][16];
  __shared__ float LNs[4][2][16];
  __shared__ float LNq[4][2][16];

  const int g = l >> 4;            // k-group 0..3
  const int m16 = l & 15;

  // --- Q fragments (A operand: row = l&15, k = g*8+j) ---
  bf16x8 qf[4];
  {
    const ushort* qsrc = qb + (size_t)(t0 + m16)*E_DIM + h*DH + g*8;
    #pragma unroll
    for (int kk=0;kk<4;++kk) qf[kk] = *(const bf16x8*)(qsrc + kk*32);
  }
  // --- per-row M (C-layout rows: t = g*4 + r) ---
  const int trowbase = t0 + g*4;
  float Mreg[4];
  #pragma unroll
  for (int r=0;r<4;++r) Mreg[r] = Mxb[h*S_LEN + trowbase + r];

  f32x4 accPV[4];
  #pragma unroll
  for (int b=0;b<4;++b){ accPV[b][0]=0.f; accPV[b][1]=0.f; accPV[b][2]=0.f; accPV[b][3]=0.f; }
  float rs[4] = {0.f,0.f,0.f,0.f};

  // --- staging address precompute (thread-level slots) ---
  const int ks = tid>>4, kj = tid&15;
  const int kc = kj ^ (ks & 7);
  const ushort* kg = kb + (size_t)ks*E_DIM + h*DH + kc*8;
  const int vd = tid>>2, vj = tid&3;
  const int vc = vj ^ ((vd>>1)&3);
  const ushort* vg = vt + ((size_t)(h*DH + vd))*S_LEN + vc*8;

  // prologue: stage kt=0
  uint4 kreg = *(const uint4*)kg;
  uint4 vreg = *(const uint4*)vg;
  *(uint4*)&Kb[0][tid*8] = kreg;
  *(uint4*)&Vb[0][tid*8] = vreg;
  __syncthreads();

  int cur = 0;
  const int srow = nb*16 + m16;          // s column (C layout) == K-frag row
  for (int kt=0; kt<NT; ++kt){
    const int sk0 = kt*32;
    const bool have_next = (kt+1 < NT);
    if (have_next){
      kreg = *(const uint4*)(kg + (size_t)(sk0+32)*E_DIM);
      vreg = *(const uint4*)(vg + (sk0+32));
    }
    const bool active = (kt <= kt_hi);
    if (active){
      // --- QK^T (16x16, this wave's nb half) ---
      f32x4 s0, s1;
      s0[0]=0.f;s0[1]=0.f;s0[2]=0.f;s0[3]=0.f;
      s1[0]=0.f;s1[1]=0.f;s1[2]=0.f;s1[3]=0.f;
      const int sw = srow & 7;
      bf16x8 kf0 = *(const bf16x8*)&Kb[cur][(srow*16 + ((0*4+g) ^ sw))*8];
      bf16x8 kf1 = *(const bf16x8*)&Kb[cur][(srow*16 + ((1*4+g) ^ sw))*8];
      bf16x8 kf2 = *(const bf16x8*)&Kb[cur][(srow*16 + ((2*4+g) ^ sw))*8];
      bf16x8 kf3 = *(const bf16x8*)&Kb[cur][(srow*16 + ((3*4+g) ^ sw))*8];
      s0 = __builtin_amdgcn_mfma_f32_16x16x32_bf16(qf[0], kf0, s0, 0, 0, 0);
      s1 = __builtin_amdgcn_mfma_f32_16x16x32_bf16(qf[1], kf1, s1, 0, 0, 0);
      s0 = __builtin_amdgcn_mfma_f32_16x16x32_bf16(qf[2], kf2, s0, 0, 0, 0);
      s1 = __builtin_amdgcn_mfma_f32_16x16x32_bf16(qf[3], kf3, s1, 0, 0, 0);
      // weights + mask + rowsum + P write
      const float msv = mbb[h*S_LEN + sk0 + srow];
      const int sg = sk0 + srow;
      #pragma unroll
      for (int r=0;r<4;++r){
        float val = (s0[r] + s1[r]) * __expf(msv - Mreg[r]);
        float wv = (sg <= trowbase + r) ? val : 0.f;
        rs[r] += wv;
        Pl[st][g*4+r][srow] = f2bf(wv);
      }
    }
    __syncthreads();                       // P visible (block-wide)
    if (have_next){                        // safe: prev readers of cur^1 done
      *(uint4*)&Kb[cur^1][tid*8] = kreg;
      *(uint4*)&Vb[cur^1][tid*8] = vreg;
    }
    if (active){
      // --- PV: A = P (16x32), B = Vt blocks (this wave's dh half) ---
      bf16x8 pf = *(const bf16x8*)&Pl[st][m16][g*8];
      #pragma unroll
      for (int b=0;b<4;++b){
        const int d = (nb*4+b)*16 + m16;
        bf16x8 vf = *(const bf16x8*)&Vb[cur][(d*4 + (g ^ ((d>>1)&3)))*8];
        accPV[b] = __builtin_amdgcn_mfma_f32_16x16x32_bf16(pf, vf, accPV[b], 0, 0, 0);
      }
    }
    __syncthreads();                       // all reads of cur done; writes to cur^1 done
    cur ^= 1;
  }

  // ---------------- epilogue ----------------
  #pragma unroll
  for (int r=0;r<4;++r){
    rs[r] += __shfl_xor(rs[r], 1, 64);
    rs[r] += __shfl_xor(rs[r], 2, 64);
    rs[r] += __shfl_xor(rs[r], 4, 64);
    rs[r] += __shfl_xor(rs[r], 8, 64);
  }
  if (m16 == 0){
    #pragma unroll
    for (int r=0;r<4;++r) rsC[st][nb][g*4+r] = rs[r];
  }
  __syncthreads();
  float inv[4];
  #pragma unroll
  for (int r=0;r<4;++r){
    const int tg = trowbase + r;
    float rstot = rsC[st][0][g*4+r] + rsC[st][1][g*4+r];
    float en = __expf(-(csb[h*S_LEN+tg] + Mreg[r]));
    inv[r] = 1.f/(fmaxf(fabsf(rstot), en) + 1e-6f);
  }
  float hv[4][4]; float ps[4]={0.f,0.f,0.f,0.f}, ps2[4]={0.f,0.f,0.f,0.f};
  #pragma unroll
  for (int b=0;b<4;++b){
    #pragma unroll
    for (int r=0;r<4;++r){
      float x = accPV[b][r]*inv[r];
      hv[b][r] = x; ps[r] += x; ps2[r] += x*x;
    }
  }
  #pragma unroll
  for (int r=0;r<4;++r){
    ps[r]  += __shfl_xor(ps[r], 1, 64);  ps2[r] += __shfl_xor(ps2[r], 1, 64);
    ps[r]  += __shfl_xor(ps[r], 2, 64);  ps2[r] += __shfl_xor(ps2[r], 2, 64);
    ps[r]  += __shfl_xor(ps[r], 4, 64);  ps2[r] += __shfl_xor(ps2[r], 4, 64);
    ps[r]  += __shfl_xor(ps[r], 8, 64);  ps2[r] += __shfl_xor(ps2[r], 8, 64);
  }
  if (m16 == 0){
    #pragma unroll
    for (int r=0;r<4;++r){ LNs[st][nb][g*4+r] = ps[r]; LNq[st][nb][g*4+r] = ps2[r]; }
  }
  __syncthreads();
  float nwv[4];
  #pragma unroll
  for (int b=0;b<4;++b) nwv[b] = nw[h*DH + (nb*4+b)*16 + m16];
  #pragma unroll
  for (int r=0;r<4;++r){
    float s1v = LNs[st][0][g*4+r] + LNs[st][1][g*4+r];
    float s2v = LNq[st][0][g*4+r] + LNq[st][1][g*4+r];
    float mean = s1v * (1.f/128.f);
    float var  = s2v * (1.f/128.f) - mean*mean;
    float rstd = rsqrtf(var + 1e-5f);
    const int tg = trowbase + r;
    float* orow = out + (size_t)tg*E_DIM + h*DH;
    #pragma unroll
    for (int b=0;b<4;++b){
      orow[(nb*4+b)*16 + m16] = (hv[b][r]-mean)*rstd*nwv[b];
    }
  }
}

extern "C" void kernel_launch(void* const* d_in, const int* in_sizes, int n_in,
                              void* d_out, int out_size, void* d_ws, size_t ws_size,
                              hipStream_t stream) {
  const float* q   = (const float*)d_in[0];
  const float* k   = (const float*)d_in[1];
  const float* v   = (const float*)d_in[2];
  const float* igw = (const float*)d_in[3];
  const float* igb = (const float*)d_in[4];
  const float* fgw = (const float*)d_in[5];
  const float* fgb = (const float*)d_in[6];
  const float* nw  = (const float*)d_in[7];
  float* outp = (float*)d_out;

  float* ws  = (float*)d_ws;
  float* ig  = ws;                 // NH*S
  float* lsf = ws + 1*NHEAD*S_LEN;
  float* csb = ws + 2*NHEAD*S_LEN;
  float* Mb  = ws + 3*NHEAD*S_LEN;
  float* mbf = ws + 4*NHEAD*S_LEN;
  ushort* qbb = (ushort*)(ws + 5*NHEAD*S_LEN);          // S*E bf16
  ushort* kbb = qbb + (size_t)S_LEN*E_DIM;              // S*E bf16
  ushort* vtb = kbb + (size_t)S_LEN*E_DIM;              // E*S bf16 (per-head transposed)

  gates_kernel<<<S_LEN, 256, 0, stream>>>(q, k, v, igw, igb, fgw, fgb, ig, lsf);
  scan_kernel<<<NHEAD, 256, 0, stream>>>(ig, lsf, csb, Mb, mbf);
  qkconv<<<(S_LEN*E_DIM/4)/256, 256, 0, stream>>>(q, k, qbb, kbb);
  vtrans<<<dim3(S_LEN/64, DH/64, NHEAD), 256, 0, stream>>>(v, vtb);
  mlstm_mfma<<<dim3(NHEAD, 32), 512, 0, stream>>>(qbb, kbb, vtb, csb, Mb, mbf, nw, outp);
}